// Round 6
// baseline (1490.233 us; speedup 1.0000x reference)
//
#include <hip/hip_runtime.h>
#include <math.h>

typedef unsigned int u32;
typedef unsigned long long u64;

#define HWSZ 16384
#define NCAND 1000
#define CAP 1024
#define NDET 100

__device__ __forceinline__ float sigmoidf_(float x) {
  return 1.0f / (1.0f + expf(-x));
}

// ---------------------------------------------------------------------------
// Fused obj+cls heads — round-15: 64-px tile, fit the immovable 64-VGPR cap.
//
// MEASURED HISTORY (stable facts, do not retry):
//  - 64-VGPR allocation target is IMMOVABLE (launch_bounds, waves_per_eu
//    both ignored; 6 configs). Any design needing >~60 live regs spills.
//  - scalar-W path: pins at 55% VALUBusy (scalar-cache miss serialization),
//    580us heads. VMEM-W per-lane addressing: spills (dead end).
//  - r5 LDS-window W (128-px tile, acc 32): 55.6% busy, ~20B/thread spill
//    (WRITE 62MB). Structure sound, liveness sat ON the 64 ceiling.
//
// ROUND-15: halve the per-thread tile -> 512 blocks x (256 rows x 64 px),
// 1 px/lane, acc[16] scalars (16 regs). Liveness ~45 < 64: NO SPILL.
// X tile 64KB -> LDS ~75KB -> 2 blocks/CU (32 waves/CU): cross-block TLP
// hides barrier/DS stalls for the first time. W path = r5's validated LDS
// double-buffered 4-wide window, prefetch-early/write-late, one barrier per
// window; W reads are wave-uniform broadcast ds_read_b128 (in-order lgkmcnt).
// Arithmetic BIT-IDENTICAL: per output, k = 0..255 ascending, same FMA
// contraction (wv.x..wv.w = k..k+3), operands bit-copied through LDS.
// Tripwires: WRITE_SIZE>=10MB -> spill (shrink further or stop);
// VALUBusy ~55% + no spill + high occupancy -> family ceiling -> tail work.
// ---------------------------------------------------------------------------
template <int NROWS, bool FULLROWS>
__device__ __forceinline__ void run_gemm64(const float* __restrict__ Wm,
                                           const float (*X)[64],
                                           float (*Wb)[1024], int tid,
                                           int rbase, int ln, float acc[16]) {
#pragma unroll
  for (int r = 0; r < 16; ++r) acc[r] = 0.f;
  const int srow = tid >> 2;     // staged row 0..255 (4 threads/row)
  const int sq = tid & 3;        // k-offset within 4-wide window
  const bool sg = srow < NROWS;  // stage guard
  const bool cg = rbase < NROWS; // compute guard

  // prologue: stage window 0 into buffer 0
  if (sg) Wb[0][srow * 4 + sq] = Wm[(size_t)srow * 256 + sq];
  __syncthreads();

#pragma unroll 1
  for (int wn = 0; wn < 64; ++wn) {
    const int buf = wn & 1;
    // prefetch-early: global load for window wn+1 (1 float/thread, from L2)
    float nv;
    const bool pre = sg && (wn + 1 < 64);
    if (pre) nv = Wm[(size_t)srow * 256 + (wn + 1) * 4 + sq];

    if (cg) {
      const float xv0 = X[wn * 4 + 0][ln];
      const float xv1 = X[wn * 4 + 1][ln];
      const float xv2 = X[wn * 4 + 2][ln];
      const float xv3 = X[wn * 4 + 3][ln];
#pragma unroll
      for (int r = 0; r < 16; ++r) {
        if (FULLROWS || rbase + r < NROWS) {
          const float4 wv = *(const float4*)&Wb[buf][(rbase + r) * 4];
          acc[r] += wv.x * xv0;
          acc[r] += wv.y * xv1;
          acc[r] += wv.z * xv2;
          acc[r] += wv.w * xv3;
        }
      }
    }
    // write-late: publish window wn+1 into the other buffer, then barrier
    if (pre) Wb[buf ^ 1][srow * 4 + sq] = nv;
    __syncthreads();
  }
}

__global__ __launch_bounds__(1024) void heads_fused(
    const float* __restrict__ feat, const float* __restrict__ ow_in,
    const float* __restrict__ ob_in, const float* __restrict__ ow_hid,
    const float* __restrict__ ob_hid, const float* __restrict__ ow_out,
    const float* __restrict__ ob_out, const float* __restrict__ cw_in,
    const float* __restrict__ cb_in, const float* __restrict__ cw_hid,
    const float* __restrict__ cb_hid, const float* __restrict__ cw_out,
    const float* __restrict__ cb_out, float* __restrict__ score,
    int* __restrict__ label) {
  __shared__ __align__(16) float X[256][64];   // 64 KB
  __shared__ __align__(16) float Wb[2][1024];  // 8 KB W window double-buffer
  __shared__ float objL[64];
  __shared__ float smax[5][64];
  __shared__ int sarg[5][64];
  // total ~76.5 KB -> 2 blocks/CU (32 waves/CU)

  const int tid = threadIdx.x;
  const int wid = __builtin_amdgcn_readfirstlane(tid >> 6);
  const int ln = tid & 63;
  const int rbase = wid * 16;
  const int batch = blockIdx.x >> 8;            // 512 blocks: 2 x 256 tiles
  const int pbase = (blockIdx.x & 255) * 64;
  const float* fb = feat + (size_t)batch * 256 * HWSZ;

  float acc[16];

  for (int head = 0; head < 2; ++head) {
    const float* w_in = head ? cw_in : ow_in;
    const float* b_in = head ? cb_in : ob_in;
    const float* w_hid = head ? cw_hid : ow_hid;
    const float* b_hid = head ? cb_hid : ob_hid;

    // ---- stage feat -> X (256 rows x 64 px, coalesced float4) ----
#pragma unroll
    for (int m = 0; m < 4; ++m) {
      int f4 = tid + 1024 * m;
      int c = f4 >> 4, col4 = (f4 & 15) * 4;
      *(float4*)&X[c][col4] =
          *(const float4*)(fb + (size_t)c * HWSZ + pbase + col4);
    }
    __syncthreads();

    // ---- 5 GEMM stages (in-conv + 4 residual hidden) ----
    for (int s = 0; s < 5; ++s) {
      const float* Wm = (s == 0) ? w_in : (w_hid + (size_t)(s - 1) * 65536);
      const float* bs = (s == 0) ? b_in : (b_hid + (s - 1) * 256);
      run_gemm64<256, true>(Wm, X, Wb, tid, rbase, ln, acc);
      // run_gemm64 ends with a barrier: all X reads complete -> safe to write.
#pragma unroll
      for (int r = 0; r < 16; ++r) {
        float v = acc[r] + bs[rbase + r];
        if (s > 0) v += X[rbase + r][ln];  // residual: h + (conv + b)
        X[rbase + r][ln] = v;
      }
      __syncthreads();  // X writes visible before next stage reads window 0
    }

    if (head == 0) {
      // ---- obj out: row 0 only ----
      run_gemm64<2, false>(ow_out, X, Wb, tid, rbase, ln, acc);
      if (wid == 0) {
        objL[ln] = sigmoidf_(acc[0] + ob_out[0]);
      }
      __syncthreads();  // objL visible; X reads drained before restage
    } else {
      // ---- cls out: 80 class rows over waves 0..4 ----
      run_gemm64<80, true>(cw_out, X, Wb, tid, rbase, ln, acc);
      if (rbase < 80) {
        float ob = objL[ln];
        float best = -1.f;
        int ba = 0;
#pragma unroll
        for (int r = 0; r < 16; ++r) {
          float s0 = sigmoidf_(acc[r] + cb_out[rbase + r]) * ob;
          if (s0 > best) {
            best = s0;
            ba = rbase + r;
          }
        }
        smax[wid][ln] = best;
        sarg[wid][ln] = ba;
      }
      __syncthreads();
      if (tid < 64) {
        float best = -1.f;
        int ba = 0;
        for (int g = 0; g < 5; ++g) {  // ascending class blocks: first-max wins
          float m = smax[g][tid];
          if (m > best) {
            best = m;
            ba = sarg[g][tid];
          }
        }
        score[batch * HWSZ + pbase + tid] = best;
        label[batch * HWSZ + pbase + tid] = ba;
      }
    }
  }
}

// ---------------------------------------------------------------------------
// ENTIRE box head in one kernel: 256 blocks x 8 candidates (validated r3-r9).
// ---------------------------------------------------------------------------
__global__ __launch_bounds__(1024) void box_all(
    const float* __restrict__ feat, const int* __restrict__ cand_idx,
    const float* __restrict__ w_in, const float* __restrict__ b_in,
    const float* __restrict__ w_hid, const float* __restrict__ b_hid,
    const float* __restrict__ w_out, const float* __restrict__ b_out,
    float* __restrict__ cand_box) {
  __shared__ float h[256][8];  // 8 KB
  const int tid = threadIdx.x;
  const int batch = blockIdx.x >> 7;
  const int cbase = (blockIdx.x & 127) * 8;
  const float* fb = feat + (size_t)batch * 256 * HWSZ;

  for (int i = tid; i < 2048; i += 1024) {
    int k = i >> 3, c = i & 7;
    int r = cbase + c;
    float v = 0.f;
    if (r < NCAND) {
      int hw = cand_idx[batch * CAP + r];
      v = fb[(size_t)k * HWSZ + hw];
    }
    h[k][c] = v;
  }
  __syncthreads();

  const int wid = tid >> 6, ln = tid & 63;
  const int c = ln & 7, rr = ln >> 3;
  const int r0 = wid * 16 + rr, r1 = wid * 16 + 8 + rr;

  for (int s = 0; s < 5; ++s) {
    const float* Wm = (s == 0) ? w_in : (w_hid + (size_t)(s - 1) * 65536);
    const float* bs = (s == 0) ? b_in : (b_hid + (s - 1) * 256);
    float a0 = 0.f, a1 = 0.f;
    for (int kb = 0; kb < 64; ++kb) {
      float4 w0 = *(const float4*)&Wm[(size_t)r0 * 256 + kb * 4];
      float4 w1 = *(const float4*)&Wm[(size_t)r1 * 256 + kb * 4];
      float x0 = h[kb * 4 + 0][c], x1 = h[kb * 4 + 1][c];
      float x2 = h[kb * 4 + 2][c], x3 = h[kb * 4 + 3][c];
      a0 += w0.x * x0;
      a0 += w0.y * x1;
      a0 += w0.z * x2;
      a0 += w0.w * x3;
      a1 += w1.x * x0;
      a1 += w1.y * x1;
      a1 += w1.z * x2;
      a1 += w1.w * x3;
    }
    __syncthreads();
    float v0 = a0 + bs[r0], v1 = a1 + bs[r1];
    if (s > 0) {
      v0 += h[r0][c];
      v1 += h[r1][c];
    }
    h[r0][c] = v0;
    h[r1][c] = v1;
    __syncthreads();
  }

  if (tid < 32) {
    int row = tid >> 3, cc = tid & 7;
    int r = cbase + cc;
    if (r < NCAND) {
      float s = 0.f;
      for (int k = 0; k < 256; ++k) s += w_out[row * 256 + k] * h[k][cc];
      s += b_out[row];
      float e = expf(s) * 8.f;
      int hw = cand_idx[batch * CAP + r];
      int hh = hw >> 7, wwp = hw & 127;
      float px = (wwp + 0.5f) * 8.f, py = (hh + 0.5f) * 8.f;
      float coord = (row == 0)   ? px - e
                    : (row == 1) ? py - e
                    : (row == 2) ? px + e
                                 : py + e;
      cand_box[(size_t)(batch * CAP + r) * 4 + row] = coord;
    }
  }
}

// ---------------------------------------------------------------------------
// Exact top-1000 per batch (bitwise-validated rounds 1-9). Skip the
// 2048-wide tie bitonic when only one element equals the threshold (the
// overwhelmingly common case for continuous scores); general path kept.
// ---------------------------------------------------------------------------
__device__ __forceinline__ void suffix2048(u32* hist, int tid) {
  for (int d = 1; d < 2048; d <<= 1) {
    u32 v0 = hist[tid] + ((tid + d < 2048) ? hist[tid + d] : 0u);
    u32 v1 =
        hist[tid + 1024] + ((tid + 1024 + d < 2048) ? hist[tid + 1024 + d] : 0u);
    __syncthreads();
    hist[tid] = v0;
    hist[tid + 1024] = v1;
    __syncthreads();
  }
}

__global__ __launch_bounds__(1024) void topk_kernel(
    const float* __restrict__ score, const int* __restrict__ label,
    float* __restrict__ cand_sc, int* __restrict__ cand_idx,
    int* __restrict__ cand_lab) {
  __shared__ u32 hist[2048];
  __shared__ u64 buf[CAP];
  __shared__ u32 tiebuf[2048];
  __shared__ int sres[2];
  __shared__ int cA, cT;
  const int tid = threadIdx.x;
  const int b = blockIdx.x;
  const int base = b * HWSZ;
  u32 bits[16];
#pragma unroll
  for (int m = 0; m < 16; ++m)
    bits[m] = __float_as_uint(score[base + tid + 1024 * m]);

  int K = NCAND;
  u32 hi = 0;
  u32 thresh = 0;
  for (int lev = 0; lev < 3; ++lev) {
    hist[tid] = 0;
    hist[tid + 1024] = 0;
    __syncthreads();
#pragma unroll
    for (int m = 0; m < 16; ++m) {
      u32 v = bits[m];
      bool ok;
      int bin;
      if (lev == 0) {
        ok = true;
        bin = v >> 21;
      } else if (lev == 1) {
        ok = ((v >> 21) == hi);
        bin = (v >> 10) & 2047;
      } else {
        ok = ((v >> 10) == hi);
        bin = v & 1023;
      }
      if (ok) atomicAdd(&hist[bin], 1u);
    }
    __syncthreads();
    suffix2048(hist, tid);
#pragma unroll
    for (int e = 0; e < 2; ++e) {
      int i = tid + e * 1024;
      int Si = (int)hist[i];
      int Sn = (i + 1 < 2048) ? (int)hist[i + 1] : 0;
      if (Si >= K && Sn < K) {
        sres[0] = i;
        sres[1] = Sn;
      }
    }
    __syncthreads();
    int B = sres[0];
    K -= sres[1];
    if (lev == 0) hi = (u32)B;
    else if (lev == 1) hi = (hi << 11) | (u32)B;
    else thresh = (hi << 10) | (u32)B;
    __syncthreads();
  }
  const int T = K;

  if (tid == 0) {
    cA = 0;
    cT = 0;
  }
  __syncthreads();
#pragma unroll
  for (int m = 0; m < 16; ++m) {
    u32 v = bits[m];
    int idxp = tid + 1024 * m;
    if (v > thresh) {
      int pos = atomicAdd(&cA, 1);
      buf[pos] = ((u64)(~v) << 32) | (u32)idxp;
    } else if (v == thresh) {
      int pos = atomicAdd(&cT, 1);
      if (pos < 2048) tiebuf[pos] = (u32)idxp;
    }
  }
  __syncthreads();
  const int A = cA;
  int nT = cT < 2048 ? cT : 2048;
  for (int i = tid; i < 2048; i += 1024)
    if (i >= nT) tiebuf[i] = 0xFFFFFFFFu;
  __syncthreads();
  if (nT > 1) {  // sort ties ascending by pixel index (rare path)
    for (int k = 2; k <= 2048; k <<= 1)
      for (int j = k >> 1; j > 0; j >>= 1) {
#pragma unroll
        for (int e = 0; e < 2; ++e) {
          int i = tid + e * 1024;
          int l = i ^ j;
          if (l > i) {
            u32 a = tiebuf[i], bb = tiebuf[l];
            bool up = ((i & k) == 0);
            if ((a > bb) == up) {
              tiebuf[i] = bb;
              tiebuf[l] = a;
            }
          }
        }
        __syncthreads();
      }
  }
  for (int t2 = tid; t2 < T; t2 += 1024)
    buf[A + t2] = ((u64)(~thresh) << 32) | tiebuf[t2];
  for (int i = tid; i < CAP; i += 1024)
    if (i >= NCAND) buf[i] = 0xFFFFFFFFFFFFFFFFull;
  __syncthreads();
  for (int k = 2; k <= 1024; k <<= 1)
    for (int j = k >> 1; j > 0; j >>= 1) {
      int i = tid, l = i ^ j;
      if (l > i) {
        u64 a = buf[i], bb = buf[l];
        bool up = ((i & k) == 0);
        if ((a > bb) == up) {
          buf[i] = bb;
          buf[l] = a;
        }
      }
      __syncthreads();
    }
  if (tid < NCAND) {
    u64 kv = buf[tid];
    u32 sb = ~(u32)(kv >> 32);
    int pix = (int)(kv & 0xFFFFFFFFull);
    cand_sc[b * CAP + tid] = __uint_as_float(sb);
    cand_idx[b * CAP + tid] = pix;
    cand_lab[b * CAP + tid] = label[base + pix];
  }
}

// ---------------------------------------------------------------------------
// NMS mask + fused sequential-suppress/assemble (unchanged, validated).
// ---------------------------------------------------------------------------
__global__ __launch_bounds__(1024) void nms_mask(
    const float* __restrict__ cand_box, u64* __restrict__ mask) {
  int bid = blockIdx.x;
  int b = bid / NCAND, i = bid % NCAND;
  int j = threadIdx.x;
  const float* bi = cand_box + (size_t)(b * CAP + i) * 4;
  float ix1 = bi[0], iy1 = bi[1], ix2 = bi[2], iy2 = bi[3];
  bool pred = false;
  if (j < NCAND && j > i) {
    const float* bj = cand_box + (size_t)(b * CAP + j) * 4;
    float jx1 = bj[0], jy1 = bj[1], jx2 = bj[2], jy2 = bj[3];
    float ai = fmaxf(ix2 - ix1, 0.f) * fmaxf(iy2 - iy1, 0.f);
    float aj = fmaxf(jx2 - jx1, 0.f) * fmaxf(jy2 - jy1, 0.f);
    float lx = fmaxf(ix1, jx1), ly = fmaxf(iy1, jy1);
    float rx = fminf(ix2, jx2), ry = fminf(iy2, jy2);
    float w = fmaxf(rx - lx, 0.f), h = fmaxf(ry - ly, 0.f);
    float inter = w * h;
    float iou = inter / (ai + aj - inter + 1e-6f);
    pred = iou > 0.65f;
  }
  u64 word = __ballot(pred);
  if ((j & 63) == 0) mask[(size_t)b * 16384 + i * 16 + (j >> 6)] = word;
}

__global__ void nms_finish(const u64* __restrict__ mask,
                           const float* __restrict__ cand_sc,
                           const int* __restrict__ cand_lab,
                           const float* __restrict__ cand_box,
                           float* __restrict__ out) {
  __shared__ u64 M[16000];
  int b = blockIdx.x, lane = threadIdx.x;  // 64 threads
  for (int m = lane; m < 16000; m += 64) M[m] = mask[(size_t)b * 16384 + m];
  __syncthreads();
  u64 kw = 0ull;
  if (lane < 15) kw = ~0ull;
  else if (lane == 15) kw = (1ull << 40) - 1;
  for (int i = 0; i < NCAND; ++i) {
    u64 wi = __shfl(kw, i >> 6);
    if ((wi >> (i & 63)) & 1ull) {
      if (lane < 16) kw &= ~M[i * 16 + lane];
    }
  }
  u64 valid = 0ull;
  if (lane < 15) valid = ~0ull;
  else if (lane == 15) valid = (1ull << 40) - 1;
  kw &= valid;
  u64 sup = valid & ~kw;
  int ck = __popcll(kw), cs = __popcll(sup);
  int preK = 0, preS = 0, totK = 0;
  for (int q = 0; q < 16; ++q) {
    int vk = __shfl(ck, q), vs = __shfl(cs, q);
    if (q < lane) {
      preK += vk;
      preS += vs;
    }
    totK += vk;
  }
  float* obox = out;
  float* osc = out + 2 * NDET * 4;
  float* olab = out + 2 * NDET * 4 + 2 * NDET;
  if (lane < 16) {
    u64 m = kw;
    int pos = preK;
    while (m) {
      int bit = __ffsll((unsigned long long)m) - 1;
      m &= m - 1;
      int j = lane * 64 + bit;
      if (pos < NDET) {
        osc[b * NDET + pos] = cand_sc[b * CAP + j];
        olab[b * NDET + pos] = (float)cand_lab[b * CAP + j];
        const float* bx = cand_box + (size_t)(b * CAP + j) * 4;
        float* dst = obox + (size_t)(b * NDET + pos) * 4;
        dst[0] = bx[0];
        dst[1] = bx[1];
        dst[2] = bx[2];
        dst[3] = bx[3];
      }
      ++pos;
    }
    m = sup;
    pos = totK + preS;
    while (m) {
      int bit = __ffsll((unsigned long long)m) - 1;
      m &= m - 1;
      int j = lane * 64 + bit;
      if (pos < NDET) {
        osc[b * NDET + pos] = 0.0f;
        olab[b * NDET + pos] = (float)cand_lab[b * CAP + j];
        const float* bx = cand_box + (size_t)(b * CAP + j) * 4;
        float* dst = obox + (size_t)(b * NDET + pos) * 4;
        dst[0] = bx[0];
        dst[1] = bx[1];
        dst[2] = bx[2];
        dst[3] = bx[3];
      }
      ++pos;
    }
  }
}

extern "C" void kernel_launch(void* const* d_in, const int* in_sizes, int n_in,
                              void* d_out, int out_size, void* d_ws,
                              size_t ws_size, hipStream_t stream) {
  (void)in_sizes;
  (void)n_in;
  (void)out_size;
  (void)ws_size;
  const float* feat = (const float*)d_in[0];
  const float* cls_w_in = (const float*)d_in[1];
  const float* cls_b_in = (const float*)d_in[2];
  const float* cls_w_hid = (const float*)d_in[3];
  const float* cls_b_hid = (const float*)d_in[4];
  const float* cls_w_out = (const float*)d_in[5];
  const float* cls_b_out = (const float*)d_in[6];
  const float* obj_w_in = (const float*)d_in[7];
  const float* obj_b_in = (const float*)d_in[8];
  const float* obj_w_hid = (const float*)d_in[9];
  const float* obj_b_hid = (const float*)d_in[10];
  const float* obj_w_out = (const float*)d_in[11];
  const float* obj_b_out = (const float*)d_in[12];
  const float* box_w_in = (const float*)d_in[13];
  const float* box_b_in = (const float*)d_in[14];
  const float* box_w_hid = (const float*)d_in[15];
  const float* box_b_hid = (const float*)d_in[16];
  const float* box_w_out = (const float*)d_in[17];
  const float* box_b_out = (const float*)d_in[18];
  float* out = (float*)d_out;

  char* w = (char*)d_ws;
  float* scoreArr = (float*)w;             // 131072 B
  int* labelArr = (int*)(w + 131072);      // 131072 B
  float* cand_sc = (float*)(w + 262144);   // 8192 B
  int* cand_idx = (int*)(w + 270336);      // 8192 B
  int* cand_lab = (int*)(w + 278528);      // 8192 B
  float* cand_box = (float*)(w + 286720);  // 32768 B
  u64* maskArr = (u64*)(w + 319488);       // 262144 B

  heads_fused<<<512, 1024, 0, stream>>>(
      feat, obj_w_in, obj_b_in, obj_w_hid, obj_b_hid, obj_w_out, obj_b_out,
      cls_w_in, cls_b_in, cls_w_hid, cls_b_hid, cls_w_out, cls_b_out, scoreArr,
      labelArr);
  topk_kernel<<<2, 1024, 0, stream>>>(scoreArr, labelArr, cand_sc, cand_idx,
                                      cand_lab);
  box_all<<<256, 1024, 0, stream>>>(feat, cand_idx, box_w_in, box_b_in,
                                    box_w_hid, box_b_hid, box_w_out, box_b_out,
                                    cand_box);
  nms_mask<<<2000, 1024, 0, stream>>>(cand_box, maskArr);
  nms_finish<<<2, 64, 0, stream>>>(maskArr, cand_sc, cand_lab, cand_box, out);
}

// Round 7
// 783.817 us; speedup vs baseline: 1.9013x; 1.9013x over previous
//
#include <hip/hip_runtime.h>
#include <math.h>

typedef unsigned int u32;
typedef unsigned long long u64;

#define HWSZ 16384
#define NCAND 1000
#define CAP 1024
#define NDET 100

__device__ __forceinline__ float sigmoidf_(float x) {
  return 1.0f / (1.0f + expf(-x));
}

// Per-wave phase stagger: break the post-barrier lockstep that makes all 4
// waves of a SIMD hit their scalar-load drains simultaneously (measured 55%
// VALUBusy == 1024/(1024+L) with L~840cyc). s_sleep arg must be an immediate.
__device__ __forceinline__ void wave_stagger(int wid) {
  switch (wid) {
    case 1: __builtin_amdgcn_s_sleep(1); break;
    case 2: __builtin_amdgcn_s_sleep(2); break;
    case 3: __builtin_amdgcn_s_sleep(3); break;
    case 4: __builtin_amdgcn_s_sleep(4); break;
    case 5: __builtin_amdgcn_s_sleep(5); break;
    case 6: __builtin_amdgcn_s_sleep(6); break;
    case 7: __builtin_amdgcn_s_sleep(7); break;
    case 8: __builtin_amdgcn_s_sleep(8); break;
    case 9: __builtin_amdgcn_s_sleep(9); break;
    case 10: __builtin_amdgcn_s_sleep(10); break;
    case 11: __builtin_amdgcn_s_sleep(11); break;
    case 12: __builtin_amdgcn_s_sleep(12); break;
    case 13: __builtin_amdgcn_s_sleep(13); break;
    case 14: __builtin_amdgcn_s_sleep(14); break;
    case 15: __builtin_amdgcn_s_sleep(15); break;
    default: break;
  }
}

// ---------------------------------------------------------------------------
// Fused obj+cls heads — round-2 structure RESTORED VERBATIM (580us heads,
// VGPR 52, no spill; best of 13 measured variants).
//
// SESSION CONCLUSIONS (6 structural variants, 6 regressions — DO NOT RETRY):
//  - VMEM-path W (any addressing): allocator pins 64 VGPR and spills acc ->
//    12.5MB scratch, 2.3x slower. launch_bounds / amdgpu_waves_per_eu are
//    both ignored for this kernel shape; 64-VGPR target is immovable.
//  - LDS-window W (128px tile): 55% busy + partial spill -> 765us.
//  - LDS-window W (64px tile, acc16): no occupancy gain (64VGPRx2048thr =
//    whole RF), 2x per-FMA DS overhead -> 1355us.
//  - The scalar-W 55%-VALUBusy wall (serialized scalar-cache misses + OOO
//    lgkmcnt full drains) is a hard local optimum for this kernel shape.
// ---------------------------------------------------------------------------
template <int NROWS, bool FULLROWS>
__device__ __forceinline__ void run_gemm(const float* __restrict__ Wm,
                                         const float (*X)[128], int rbase,
                                         int p0, float2 acc[16]) {
#pragma unroll
  for (int r = 0; r < 16; ++r) {
    acc[r].x = 0.f;
    acc[r].y = 0.f;
  }
  wave_stagger(rbase >> 4);
  if (rbase < NROWS) {
    for (int kb = 0; kb < 64; ++kb) {
      float2 xv0 = *(const float2*)&X[kb * 4 + 0][p0];
      float2 xv1 = *(const float2*)&X[kb * 4 + 1][p0];
      float2 xv2 = *(const float2*)&X[kb * 4 + 2][p0];
      float2 xv3 = *(const float2*)&X[kb * 4 + 3][p0];
#pragma unroll
      for (int r = 0; r < 16; ++r) {
        if (FULLROWS || rbase + r < NROWS) {
          const float4 wv =
              *(const float4*)(Wm + (size_t)(rbase + r) * 256 + kb * 4);
          acc[r].x += wv.x * xv0.x;
          acc[r].y += wv.x * xv0.y;
          acc[r].x += wv.y * xv1.x;
          acc[r].y += wv.y * xv1.y;
          acc[r].x += wv.z * xv2.x;
          acc[r].y += wv.z * xv2.y;
          acc[r].x += wv.w * xv3.x;
          acc[r].y += wv.w * xv3.y;
        }
      }
    }
  }
}

__global__ __launch_bounds__(1024, 4) void heads_fused(
    const float* __restrict__ feat, const float* __restrict__ ow_in,
    const float* __restrict__ ob_in, const float* __restrict__ ow_hid,
    const float* __restrict__ ob_hid, const float* __restrict__ ow_out,
    const float* __restrict__ ob_out, const float* __restrict__ cw_in,
    const float* __restrict__ cb_in, const float* __restrict__ cw_hid,
    const float* __restrict__ cb_hid, const float* __restrict__ cw_out,
    const float* __restrict__ cb_out, float* __restrict__ score,
    int* __restrict__ label) {
  __shared__ __align__(16) float X[256][128];  // 128 KB
  __shared__ float objL[128];
  __shared__ float smax[5][128];
  __shared__ int sarg[5][128];

  const int tid = threadIdx.x;
  const int wid = __builtin_amdgcn_readfirstlane(tid >> 6);
  const int ln = tid & 63;
  const int p0 = 2 * ln;
  const int rbase = wid * 16;
  const int batch = blockIdx.x >> 7;
  const int pbase = (blockIdx.x & 127) * 128;
  const float* fb = feat + (size_t)batch * 256 * HWSZ;

  for (int head = 0; head < 2; ++head) {
    const float* w_in = head ? cw_in : ow_in;
    const float* b_in = head ? cb_in : ob_in;
    const float* w_hid = head ? cw_hid : ow_hid;
    const float* b_hid = head ? cb_hid : ob_hid;

    // ---- stage feat -> X ----
#pragma unroll
    for (int m = 0; m < 8; ++m) {
      int f4 = tid + 1024 * m;
      int c = f4 >> 5, col4 = (f4 & 31) * 4;
      *(float4*)&X[c][col4] =
          *(const float4*)(fb + (size_t)c * HWSZ + pbase + col4);
    }
    __syncthreads();

    float2 acc[16];
    // ---- 5 GEMM stages (in-conv + 4 residual hidden) ----
    for (int s = 0; s < 5; ++s) {
      const float* Wm = (s == 0) ? w_in : (w_hid + (size_t)(s - 1) * 65536);
      const float* bs = (s == 0) ? b_in : (b_hid + (s - 1) * 256);
      run_gemm<256, true>(Wm, X, rbase, p0, acc);
      __syncthreads();  // all reads of X complete
#pragma unroll
      for (int r = 0; r < 16; ++r) {
        float b = bs[rbase + r];
        float2 v = make_float2(acc[r].x + b, acc[r].y + b);
        if (s > 0) {  // residual: h + (conv + b)
          v.x += X[rbase + r][p0];
          v.y += X[rbase + r][p0 + 1];
        }
        *(float2*)&X[rbase + r][p0] = v;
      }
      __syncthreads();
    }

    if (head == 0) {
      // ---- obj out: row 0 only ----
      run_gemm<2, false>(ow_out, X, rbase, p0, acc);
      if (wid == 0) {
        float bo = ob_out[0];
        objL[p0] = sigmoidf_(acc[0].x + bo);
        objL[p0 + 1] = sigmoidf_(acc[0].y + bo);
      }
      __syncthreads();  // objL visible; X reads drained before restage
    } else {
      // ---- cls out: 80 class rows over waves 0..4 ----
      run_gemm<80, true>(cw_out, X, rbase, p0, acc);
      if (rbase < 80) {
        float ob0 = objL[p0], ob1 = objL[p0 + 1];
        float best0 = -1.f, best1 = -1.f;
        int a0 = 0, a1 = 0;
#pragma unroll
        for (int r = 0; r < 16; ++r) {
          float bb = cb_out[rbase + r];
          float s0 = sigmoidf_(acc[r].x + bb) * ob0;
          float s1 = sigmoidf_(acc[r].y + bb) * ob1;
          if (s0 > best0) {
            best0 = s0;
            a0 = rbase + r;
          }
          if (s1 > best1) {
            best1 = s1;
            a1 = rbase + r;
          }
        }
        smax[wid][p0] = best0;
        sarg[wid][p0] = a0;
        smax[wid][p0 + 1] = best1;
        sarg[wid][p0 + 1] = a1;
      }
      __syncthreads();
      if (tid < 128) {
        float best = -1.f;
        int ba = 0;
        for (int g = 0; g < 5; ++g) {  // ascending class blocks: first-max wins
          float m = smax[g][tid];
          if (m > best) {
            best = m;
            ba = sarg[g][tid];
          }
        }
        score[batch * HWSZ + pbase + tid] = best;
        label[batch * HWSZ + pbase + tid] = ba;
      }
    }
  }
}

// ---------------------------------------------------------------------------
// ENTIRE box head in one kernel: 256 blocks x 8 candidates (validated).
// ---------------------------------------------------------------------------
__global__ __launch_bounds__(1024) void box_all(
    const float* __restrict__ feat, const int* __restrict__ cand_idx,
    const float* __restrict__ w_in, const float* __restrict__ b_in,
    const float* __restrict__ w_hid, const float* __restrict__ b_hid,
    const float* __restrict__ w_out, const float* __restrict__ b_out,
    float* __restrict__ cand_box) {
  __shared__ float h[256][8];  // 8 KB
  const int tid = threadIdx.x;
  const int batch = blockIdx.x >> 7;
  const int cbase = (blockIdx.x & 127) * 8;
  const float* fb = feat + (size_t)batch * 256 * HWSZ;

  for (int i = tid; i < 2048; i += 1024) {
    int k = i >> 3, c = i & 7;
    int r = cbase + c;
    float v = 0.f;
    if (r < NCAND) {
      int hw = cand_idx[batch * CAP + r];
      v = fb[(size_t)k * HWSZ + hw];
    }
    h[k][c] = v;
  }
  __syncthreads();

  const int wid = tid >> 6, ln = tid & 63;
  const int c = ln & 7, rr = ln >> 3;
  const int r0 = wid * 16 + rr, r1 = wid * 16 + 8 + rr;

  for (int s = 0; s < 5; ++s) {
    const float* Wm = (s == 0) ? w_in : (w_hid + (size_t)(s - 1) * 65536);
    const float* bs = (s == 0) ? b_in : (b_hid + (s - 1) * 256);
    float a0 = 0.f, a1 = 0.f;
    for (int kb = 0; kb < 64; ++kb) {
      float4 w0 = *(const float4*)&Wm[(size_t)r0 * 256 + kb * 4];
      float4 w1 = *(const float4*)&Wm[(size_t)r1 * 256 + kb * 4];
      float x0 = h[kb * 4 + 0][c], x1 = h[kb * 4 + 1][c];
      float x2 = h[kb * 4 + 2][c], x3 = h[kb * 4 + 3][c];
      a0 += w0.x * x0;
      a0 += w0.y * x1;
      a0 += w0.z * x2;
      a0 += w0.w * x3;
      a1 += w1.x * x0;
      a1 += w1.y * x1;
      a1 += w1.z * x2;
      a1 += w1.w * x3;
    }
    __syncthreads();
    float v0 = a0 + bs[r0], v1 = a1 + bs[r1];
    if (s > 0) {
      v0 += h[r0][c];
      v1 += h[r1][c];
    }
    h[r0][c] = v0;
    h[r1][c] = v1;
    __syncthreads();
  }

  if (tid < 32) {
    int row = tid >> 3, cc = tid & 7;
    int r = cbase + cc;
    if (r < NCAND) {
      float s = 0.f;
      for (int k = 0; k < 256; ++k) s += w_out[row * 256 + k] * h[k][cc];
      s += b_out[row];
      float e = expf(s) * 8.f;
      int hw = cand_idx[batch * CAP + r];
      int hh = hw >> 7, wwp = hw & 127;
      float px = (wwp + 0.5f) * 8.f, py = (hh + 0.5f) * 8.f;
      float coord = (row == 0)   ? px - e
                    : (row == 1) ? py - e
                    : (row == 2) ? px + e
                                 : py + e;
      cand_box[(size_t)(batch * CAP + r) * 4 + row] = coord;
    }
  }
}

// ---------------------------------------------------------------------------
// Exact top-1000 per batch. ROUND-16 CHANGE: compaction via per-wave ballot
// + popcount prefix (1 atomic/wave/bucket) instead of 16384 same-address LDS
// atomics/block (serialized, ~20us/block). Result is EXACT: buf is fully
// sorted afterward by the complete u64 key (~v,idx) and tiebuf is sorted by
// index when nT>1, so insertion order cannot affect the output. (>2048-ties
// clamp behavior was order-nondeterministic before and stays so.)
// ---------------------------------------------------------------------------
__device__ __forceinline__ void suffix2048(u32* hist, int tid) {
  for (int d = 1; d < 2048; d <<= 1) {
    u32 v0 = hist[tid] + ((tid + d < 2048) ? hist[tid + d] : 0u);
    u32 v1 =
        hist[tid + 1024] + ((tid + 1024 + d < 2048) ? hist[tid + 1024 + d] : 0u);
    __syncthreads();
    hist[tid] = v0;
    hist[tid + 1024] = v1;
    __syncthreads();
  }
}

__global__ __launch_bounds__(1024) void topk_kernel(
    const float* __restrict__ score, const int* __restrict__ label,
    float* __restrict__ cand_sc, int* __restrict__ cand_idx,
    int* __restrict__ cand_lab) {
  __shared__ u32 hist[2048];
  __shared__ u64 buf[CAP];
  __shared__ u32 tiebuf[2048];
  __shared__ int sres[2];
  __shared__ int cA, cT;
  const int tid = threadIdx.x;
  const int b = blockIdx.x;
  const int base = b * HWSZ;
  u32 bits[16];
#pragma unroll
  for (int m = 0; m < 16; ++m)
    bits[m] = __float_as_uint(score[base + tid + 1024 * m]);

  int K = NCAND;
  u32 hi = 0;
  u32 thresh = 0;
  for (int lev = 0; lev < 3; ++lev) {
    hist[tid] = 0;
    hist[tid + 1024] = 0;
    __syncthreads();
#pragma unroll
    for (int m = 0; m < 16; ++m) {
      u32 v = bits[m];
      bool ok;
      int bin;
      if (lev == 0) {
        ok = true;
        bin = v >> 21;
      } else if (lev == 1) {
        ok = ((v >> 21) == hi);
        bin = (v >> 10) & 2047;
      } else {
        ok = ((v >> 10) == hi);
        bin = v & 1023;
      }
      if (ok) atomicAdd(&hist[bin], 1u);
    }
    __syncthreads();
    suffix2048(hist, tid);
#pragma unroll
    for (int e = 0; e < 2; ++e) {
      int i = tid + e * 1024;
      int Si = (int)hist[i];
      int Sn = (i + 1 < 2048) ? (int)hist[i + 1] : 0;
      if (Si >= K && Sn < K) {
        sres[0] = i;
        sres[1] = Sn;
      }
    }
    __syncthreads();
    int B = sres[0];
    K -= sres[1];
    if (lev == 0) hi = (u32)B;
    else if (lev == 1) hi = (hi << 11) | (u32)B;
    else thresh = (hi << 10) | (u32)B;
    __syncthreads();
  }
  const int T = K;

  if (tid == 0) {
    cA = 0;
    cT = 0;
  }
  __syncthreads();
  const int lane = tid & 63;
  const u64 below = (lane == 0) ? 0ull : (~0ull >> (64 - lane));
#pragma unroll
  for (int m = 0; m < 16; ++m) {
    u32 v = bits[m];
    int idxp = tid + 1024 * m;
    const bool gt = (v > thresh);
    const bool eq = (v == thresh);
    const u64 mg = __ballot(gt);
    const u64 me = __ballot(eq);
    int wbase_g = 0, wbase_e = 0;
    if (lane == 0) {
      const int cg = __popcll(mg);
      const int ce = __popcll(me);
      if (cg) wbase_g = atomicAdd(&cA, cg);
      if (ce) wbase_e = atomicAdd(&cT, ce);
    }
    wbase_g = __shfl(wbase_g, 0);
    wbase_e = __shfl(wbase_e, 0);
    if (gt) {
      int pos = wbase_g + __popcll(mg & below);
      buf[pos] = ((u64)(~v) << 32) | (u32)idxp;
    } else if (eq) {
      int pos = wbase_e + __popcll(me & below);
      if (pos < 2048) tiebuf[pos] = (u32)idxp;
    }
  }
  __syncthreads();
  const int A = cA;
  int nT = cT < 2048 ? cT : 2048;
  for (int i = tid; i < 2048; i += 1024)
    if (i >= nT) tiebuf[i] = 0xFFFFFFFFu;
  __syncthreads();
  if (nT > 1) {  // sort ties ascending by pixel index (rare path)
    for (int k = 2; k <= 2048; k <<= 1)
      for (int j = k >> 1; j > 0; j >>= 1) {
#pragma unroll
        for (int e = 0; e < 2; ++e) {
          int i = tid + e * 1024;
          int l = i ^ j;
          if (l > i) {
            u32 a = tiebuf[i], bb = tiebuf[l];
            bool up = ((i & k) == 0);
            if ((a > bb) == up) {
              tiebuf[i] = bb;
              tiebuf[l] = a;
            }
          }
        }
        __syncthreads();
      }
  }
  for (int t2 = tid; t2 < T; t2 += 1024)
    buf[A + t2] = ((u64)(~thresh) << 32) | tiebuf[t2];
  for (int i = tid; i < CAP; i += 1024)
    if (i >= NCAND) buf[i] = 0xFFFFFFFFFFFFFFFFull;
  __syncthreads();
  for (int k = 2; k <= 1024; k <<= 1)
    for (int j = k >> 1; j > 0; j >>= 1) {
      int i = tid, l = i ^ j;
      if (l > i) {
        u64 a = buf[i], bb = buf[l];
        bool up = ((i & k) == 0);
        if ((a > bb) == up) {
          buf[i] = bb;
          buf[l] = a;
        }
      }
      __syncthreads();
    }
  if (tid < NCAND) {
    u64 kv = buf[tid];
    u32 sb = ~(u32)(kv >> 32);
    int pix = (int)(kv & 0xFFFFFFFFull);
    cand_sc[b * CAP + tid] = __uint_as_float(sb);
    cand_idx[b * CAP + tid] = pix;
    cand_lab[b * CAP + tid] = label[base + pix];
  }
}

// ---------------------------------------------------------------------------
// NMS mask + fused sequential-suppress/assemble (unchanged, validated).
// ---------------------------------------------------------------------------
__global__ __launch_bounds__(1024) void nms_mask(
    const float* __restrict__ cand_box, u64* __restrict__ mask) {
  int bid = blockIdx.x;
  int b = bid / NCAND, i = bid % NCAND;
  int j = threadIdx.x;
  const float* bi = cand_box + (size_t)(b * CAP + i) * 4;
  float ix1 = bi[0], iy1 = bi[1], ix2 = bi[2], iy2 = bi[3];
  bool pred = false;
  if (j < NCAND && j > i) {
    const float* bj = cand_box + (size_t)(b * CAP + j) * 4;
    float jx1 = bj[0], jy1 = bj[1], jx2 = bj[2], jy2 = bj[3];
    float ai = fmaxf(ix2 - ix1, 0.f) * fmaxf(iy2 - iy1, 0.f);
    float aj = fmaxf(jx2 - jx1, 0.f) * fmaxf(jy2 - jy1, 0.f);
    float lx = fmaxf(ix1, jx1), ly = fmaxf(iy1, jy1);
    float rx = fminf(ix2, jx2), ry = fminf(iy2, jy2);
    float w = fmaxf(rx - lx, 0.f), h = fmaxf(ry - ly, 0.f);
    float inter = w * h;
    float iou = inter / (ai + aj - inter + 1e-6f);
    pred = iou > 0.65f;
  }
  u64 word = __ballot(pred);
  if ((j & 63) == 0) mask[(size_t)b * 16384 + i * 16 + (j >> 6)] = word;
}

__global__ void nms_finish(const u64* __restrict__ mask,
                           const float* __restrict__ cand_sc,
                           const int* __restrict__ cand_lab,
                           const float* __restrict__ cand_box,
                           float* __restrict__ out) {
  __shared__ u64 M[16000];
  int b = blockIdx.x, lane = threadIdx.x;  // 64 threads
  for (int m = lane; m < 16000; m += 64) M[m] = mask[(size_t)b * 16384 + m];
  __syncthreads();
  u64 kw = 0ull;
  if (lane < 15) kw = ~0ull;
  else if (lane == 15) kw = (1ull << 40) - 1;
  for (int i = 0; i < NCAND; ++i) {
    u64 wi = __shfl(kw, i >> 6);
    if ((wi >> (i & 63)) & 1ull) {
      if (lane < 16) kw &= ~M[i * 16 + lane];
    }
  }
  u64 valid = 0ull;
  if (lane < 15) valid = ~0ull;
  else if (lane == 15) valid = (1ull << 40) - 1;
  kw &= valid;
  u64 sup = valid & ~kw;
  int ck = __popcll(kw), cs = __popcll(sup);
  int preK = 0, preS = 0, totK = 0;
  for (int q = 0; q < 16; ++q) {
    int vk = __shfl(ck, q), vs = __shfl(cs, q);
    if (q < lane) {
      preK += vk;
      preS += vs;
    }
    totK += vk;
  }
  float* obox = out;
  float* osc = out + 2 * NDET * 4;
  float* olab = out + 2 * NDET * 4 + 2 * NDET;
  if (lane < 16) {
    u64 m = kw;
    int pos = preK;
    while (m) {
      int bit = __ffsll((unsigned long long)m) - 1;
      m &= m - 1;
      int j = lane * 64 + bit;
      if (pos < NDET) {
        osc[b * NDET + pos] = cand_sc[b * CAP + j];
        olab[b * NDET + pos] = (float)cand_lab[b * CAP + j];
        const float* bx = cand_box + (size_t)(b * CAP + j) * 4;
        float* dst = obox + (size_t)(b * NDET + pos) * 4;
        dst[0] = bx[0];
        dst[1] = bx[1];
        dst[2] = bx[2];
        dst[3] = bx[3];
      }
      ++pos;
    }
    m = sup;
    pos = totK + preS;
    while (m) {
      int bit = __ffsll((unsigned long long)m) - 1;
      m &= m - 1;
      int j = lane * 64 + bit;
      if (pos < NDET) {
        osc[b * NDET + pos] = 0.0f;
        olab[b * NDET + pos] = (float)cand_lab[b * CAP + j];
        const float* bx = cand_box + (size_t)(b * CAP + j) * 4;
        float* dst = obox + (size_t)(b * NDET + pos) * 4;
        dst[0] = bx[0];
        dst[1] = bx[1];
        dst[2] = bx[2];
        dst[3] = bx[3];
      }
      ++pos;
    }
  }
}

extern "C" void kernel_launch(void* const* d_in, const int* in_sizes, int n_in,
                              void* d_out, int out_size, void* d_ws,
                              size_t ws_size, hipStream_t stream) {
  (void)in_sizes;
  (void)n_in;
  (void)out_size;
  (void)ws_size;
  const float* feat = (const float*)d_in[0];
  const float* cls_w_in = (const float*)d_in[1];
  const float* cls_b_in = (const float*)d_in[2];
  const float* cls_w_hid = (const float*)d_in[3];
  const float* cls_b_hid = (const float*)d_in[4];
  const float* cls_w_out = (const float*)d_in[5];
  const float* cls_b_out = (const float*)d_in[6];
  const float* obj_w_in = (const float*)d_in[7];
  const float* obj_b_in = (const float*)d_in[8];
  const float* obj_w_hid = (const float*)d_in[9];
  const float* obj_b_hid = (const float*)d_in[10];
  const float* obj_w_out = (const float*)d_in[11];
  const float* obj_b_out = (const float*)d_in[12];
  const float* box_w_in = (const float*)d_in[13];
  const float* box_b_in = (const float*)d_in[14];
  const float* box_w_hid = (const float*)d_in[15];
  const float* box_b_hid = (const float*)d_in[16];
  const float* box_w_out = (const float*)d_in[17];
  const float* box_b_out = (const float*)d_in[18];
  float* out = (float*)d_out;

  char* w = (char*)d_ws;
  float* scoreArr = (float*)w;             // 131072 B
  int* labelArr = (int*)(w + 131072);      // 131072 B
  float* cand_sc = (float*)(w + 262144);   // 8192 B
  int* cand_idx = (int*)(w + 270336);      // 8192 B
  int* cand_lab = (int*)(w + 278528);      // 8192 B
  float* cand_box = (float*)(w + 286720);  // 32768 B
  u64* maskArr = (u64*)(w + 319488);       // 262144 B

  heads_fused<<<256, 1024, 0, stream>>>(
      feat, obj_w_in, obj_b_in, obj_w_hid, obj_b_hid, obj_w_out, obj_b_out,
      cls_w_in, cls_b_in, cls_w_hid, cls_b_hid, cls_w_out, cls_b_out, scoreArr,
      labelArr);
  topk_kernel<<<2, 1024, 0, stream>>>(scoreArr, labelArr, cand_sc, cand_idx,
                                      cand_lab);
  box_all<<<256, 1024, 0, stream>>>(feat, cand_idx, box_w_in, box_b_in,
                                    box_w_hid, box_b_hid, box_w_out, box_b_out,
                                    cand_box);
  nms_mask<<<2000, 1024, 0, stream>>>(cand_box, maskArr);
  nms_finish<<<2, 64, 0, stream>>>(maskArr, cand_sc, cand_lab, cand_box, out);
}